// Round 6
// baseline (705.465 us; speedup 1.0000x reference)
//
#include <hip/hip_runtime.h>
#include <hip/hip_bf16.h>

// FujiRoutedExperts: E=32, D=1024, I=512, T=4096, K=8 (all fp32 in/out)
#define E_   32
#define D_   1024
#define I_   512
#define T_   4096
#define KTOP 8
#define TK   (T_*KTOP)          // 32768 gathered (token, slot) rows

// MFMA GEMM tiling: 128x128 tile, BK=32 (one 16x16x32 MFMA K-depth)
#define BM   128
#define BKK  32
#define MAXT (TK/BM + E_)       // 288 worst-case row-tiles
#define NBLK 128                // routing blocks (TK / 256)

// Workspace layout:
//  w[0]       idx-is-int64 flag
//  w[96..128] expert segment offsets (off[32]=TK) | w[129] tile count
//  byte 1024   int2 tiles[MAXT]                (2304 B)
//  byte 4096   int  blockHist[NBLK][E_]        (16 KB)
//  byte 20480  int  blockBase[NBLK][E_]        (16 KB)
//  byte 36864  int   tok[TK]                   (128 KB)
//  byte 167936 float wt[TK]                    (128 KB)
//  byte 524288 bf16  H[TK][I_]                 (32 MB)
#define TILES_OFF 1024
#define HIST_OFF  4096
#define BASE_OFF  20480
#define TOK_OFF   36864
#define WT_OFF    167936
#define H_OFF     524288

typedef __attribute__((ext_vector_type(8))) short short8v;   // 8 bf16 = 4 VGPR
typedef __attribute__((ext_vector_type(4))) float f32x4;     // MFMA acc

// fp32 -> bf16; compiler pairs scalar casts into v_cvt_pk_bf16_f32 (m240).
__device__ inline unsigned short f2bf(float x) {
    __hip_bfloat16 h = __float2bfloat16(x);
    union { __hip_bfloat16 h; unsigned short u; } c; c.h = h; return c.u;
}
__device__ inline short8v pack8(float4 a, float4 b) {
    short8v r;
    r[0]=(short)f2bf(a.x); r[1]=(short)f2bf(a.y); r[2]=(short)f2bf(a.z); r[3]=(short)f2bf(a.w);
    r[4]=(short)f2bf(b.x); r[5]=(short)f2bf(b.y); r[6]=(short)f2bf(b.z); r[7]=(short)f2bf(b.w);
    return r;
}

// ---------------------------------------------------------------- routing ---

// int64 indices (values 0..31, little-endian) have all odd int32 words zero.
__global__ void detect_idx64_kernel(const int* __restrict__ idx32, int* w) {
    const int lane = threadIdx.x;      // 64 threads
    int bad = 0;
#pragma unroll
    for (int j = 0; j < 4; ++j) bad |= idx32[2 * (lane + 64 * j) + 1];
    int allz = __all(bad == 0);
    if (lane == 0) w[0] = allz ? 1 : 0;
}

// Per-block 32-bin histogram in LDS; each block owns its global hist row
// (no global atomics at all).
__global__ __launch_bounds__(256) void hist_kernel(const int* __restrict__ idx32, int* w) {
    __shared__ int h[E_];
    const int tid = threadIdx.x, b = blockIdx.x;
    if (tid < E_) h[tid] = 0;
    __syncthreads();
    int i = b * 256 + tid;
    int e = w[0] ? idx32[2*i] : idx32[i];
    atomicAdd(&h[e], 1);               // LDS atomic: fast
    __syncthreads();
    if (tid < E_) ((int*)((char*)w + HIST_OFF))[b * E_ + tid] = h[tid];
}

// One wave. Lane e: serial scan over NBLK blocks -> per-block bases + expert
// totals; shfl scan over experts -> segment offsets; then emit tile list.
__global__ void scan_kernel(int* w) {
    const int lane = threadIdx.x;      // 64 threads
    int* hist = (int*)((char*)w + HIST_OFF);
    int* base = (int*)((char*)w + BASE_OFF);
    int cnt = 0;
    if (lane < E_) {
        for (int b = 0; b < NBLK; ++b) { base[b*E_ + lane] = cnt; cnt += hist[b*E_ + lane]; }
    }
    int x = cnt;
#pragma unroll
    for (int d = 1; d < 32; d <<= 1) {
        int v = __shfl_up(x, d, 64);
        if (lane >= d) x += v;
    }
    int excl = x - cnt;                // expert segment start
    if (lane < E_) {
        w[96 + lane] = excl;
        for (int b = 0; b < NBLK; ++b) base[b*E_ + lane] += excl;
    }
    if (lane == E_ - 1) w[96 + E_] = x;

    int nt_e = (lane < E_) ? (cnt + BM - 1) / BM : 0;
    int y = nt_e;
#pragma unroll
    for (int d = 1; d < 32; d <<= 1) {
        int v = __shfl_up(y, d, 64);
        if (lane >= d) y += v;
    }
    int texcl = y - nt_e;
    if (lane == E_ - 1) w[129] = y;
    int2* tiles = (int2*)((char*)w + TILES_OFF);
    for (int i = 0; i < nt_e; ++i)
        tiles[texcl + i] = make_int2(lane, excl + i * BM);
}

// Positions from per-block bases + LDS cursors (no global atomics).
__global__ __launch_bounds__(256) void scatter_kernel(const int* __restrict__ idx32,
                               const float* __restrict__ wts, int* w) {
    __shared__ int cur[E_];
    const int tid = threadIdx.x, b = blockIdx.x;
    if (tid < E_) cur[tid] = ((int*)((char*)w + BASE_OFF))[b * E_ + tid];
    __syncthreads();
    int i = b * 256 + tid;
    int e = w[0] ? idx32[2*i] : idx32[i];
    int pos = atomicAdd(&cur[e], 1);   // LDS atomic
    ((int*)  ((char*)w + TOK_OFF))[pos] = i >> 3;   // i / KTOP
    ((float*)((char*)w + WT_OFF))[pos]  = wts[i];
}

// --------------------------------------------------------------- GEMM1 ------
// H[row, n] = silu(x.Wgate[n]) * (x.Wup[n]); M=TK (gathered), N=I_, K=D_.
// LDS layout (K-major, conflict-free): buf[oct][128][8 bf16], oct = K-octet.
// Fragment read (16x16x32): lane l -> row l&15 (+frag offset), oct l>>4
//   addr16B = (oct*128 + row): 16 consecutive 16B units per 16-lane group.
// Staging write: wave-contiguous 1KB blocks. Both sides conflict-free.
__global__ __launch_bounds__(256) void gemm1_mfma(
    const float* __restrict__ hidden, const float* __restrict__ gup,
    const int* __restrict__ w, unsigned short* __restrict__ H)
{
    if ((int)blockIdx.y >= w[129]) return;
    int2 tl = ((const int2*)((const char*)w + TILES_OFF))[blockIdx.y];
    const int e = tl.x, rs = tl.y;
    const int rows = min(w[96 + e + 1] - rs, BM);
    const int* tok = (const int*)((const char*)w + TOK_OFF);

    __shared__ short As[4 * BM * 8];
    __shared__ short Bs[4 * BM * 8];
    __shared__ int tokS[BM];

    const int tid = threadIdx.x;
    if (tid < BM) tokS[tid] = tok[rs + min(tid, rows - 1)];
    __syncthreads();

    const int n0 = blockIdx.x * 64;                 // SwiGLU col block
    const float* gb = gup + (size_t)e * (2 * I_) * D_;

    // staging: this thread owns row srow, octets oct0 and oct0+2
    const int srow = tid & 127, oct0 = tid >> 7;
    const float* asrc = hidden + (size_t)tokS[srow] * D_ + oct0 * 8;
    const float* bsrc = (srow < 64 ? gb + (size_t)(n0 + srow) * D_
                                   : gb + (size_t)(I_ + n0 + srow - 64) * D_) + oct0 * 8;
    short8v* wA0 = (short8v*)&As[(oct0 * BM + srow) * 8];
    short8v* wA1 = (short8v*)&As[((oct0 + 2) * BM + srow) * 8];
    short8v* wB0 = (short8v*)&Bs[(oct0 * BM + srow) * 8];
    short8v* wB1 = (short8v*)&Bs[((oct0 + 2) * BM + srow) * 8];

    const int wid = tid >> 6, lane = tid & 63;
    const int l16 = lane & 15, koct = lane >> 4;
    const int aoff = koct * BM + wid * 32 + l16;    // 16B units
    const int boff = koct * BM + l16;

    f32x4 acc[2][8];
#pragma unroll
    for (int i = 0; i < 2; ++i)
#pragma unroll
        for (int j = 0; j < 8; ++j) acc[i][j] = (f32x4){0.f, 0.f, 0.f, 0.f};

    float4 ra0, ra1, ra2, ra3, rb0, rb1, rb2, rb3;
#define LOADREGS1(K0) { \
    ra0 = *(const float4*)(asrc + (K0));      ra1 = *(const float4*)(asrc + (K0) + 4); \
    ra2 = *(const float4*)(asrc + (K0) + 16); ra3 = *(const float4*)(asrc + (K0) + 20); \
    rb0 = *(const float4*)(bsrc + (K0));      rb1 = *(const float4*)(bsrc + (K0) + 4); \
    rb2 = *(const float4*)(bsrc + (K0) + 16); rb3 = *(const float4*)(bsrc + (K0) + 20); }

    LOADREGS1(0);
    for (int k0 = 0; k0 < D_; k0 += BKK) {
        __syncthreads();
        *wA0 = pack8(ra0, ra1);
        *wA1 = pack8(ra2, ra3);
        *wB0 = pack8(rb0, rb1);
        *wB1 = pack8(rb2, rb3);
        __syncthreads();
        if (k0 + BKK < D_) LOADREGS1(k0 + BKK);
        short8v a0 = *(const short8v*)&As[aoff * 8];
        short8v a1 = *(const short8v*)&As[(aoff + 16) * 8];
#pragma unroll
        for (int j = 0; j < 8; ++j) {
            short8v b = *(const short8v*)&Bs[(boff + j * 16) * 8];
            acc[0][j] = __builtin_amdgcn_mfma_f32_16x16x32_bf16(a0, b, acc[0][j], 0, 0, 0);
            acc[1][j] = __builtin_amdgcn_mfma_f32_16x16x32_bf16(a1, b, acc[1][j], 0, 0, 0);
        }
    }

    // SwiGLU epilogue: frag j is gate cols, j+4 is up (same lanes/rows).
    const int r0 = (lane >> 4) * 4;
#pragma unroll
    for (int mr = 0; mr < 2; ++mr)
#pragma unroll
        for (int j = 0; j < 4; ++j)
#pragma unroll
            for (int r = 0; r < 4; ++r) {
                int m = wid * 32 + mr * 16 + r0 + r;
                if (m < rows) {
                    float g = acc[mr][j][r], u = acc[mr][j + 4][r];
                    float s = g / (1.f + __expf(-g));
                    H[(size_t)(rs + m) * I_ + n0 + j * 16 + l16] = f2bf(s * u);
                }
            }
}

// --------------------------------------------------------------- GEMM2 ------
// out[tok,n] += wt * (H[row].Wd[n]); M=TK, N=D_, K=I_. Same LDS structure.
__global__ __launch_bounds__(256) void gemm2_mfma(
    const unsigned short* __restrict__ H, const float* __restrict__ down,
    const int* __restrict__ w, float* __restrict__ out)
{
    if ((int)blockIdx.y >= w[129]) return;
    int2 tl = ((const int2*)((const char*)w + TILES_OFF))[blockIdx.y];
    const int e = tl.x, rs = tl.y;
    const int rows = min(w[96 + e + 1] - rs, BM);
    const int*   tok = (const int*)  ((const char*)w + TOK_OFF);
    const float* wts = (const float*)((const char*)w + WT_OFF);

    __shared__ short As[4 * BM * 8];
    __shared__ short Bs[4 * BM * 8];
    __shared__ int   tokS[BM];
    __shared__ float wtS[BM];

    const int tid = threadIdx.x;
    if (tid < BM) {
        tokS[tid] = tok[rs + min(tid, rows - 1)];
        wtS[tid]  = (tid < rows) ? wts[rs + tid] : 0.f;
    }
    __syncthreads();

    const int n0 = blockIdx.x * 128;
    const float* db = down + (size_t)e * D_ * I_;

    const int srow = tid & 127, oct0 = tid >> 7;
    // A = H (bf16, gathered rows are contiguous); clamp final-tile overrun.
    const short* hsrc = (const short*)H + (size_t)min(rs + srow, TK - 1) * I_ + oct0 * 8;
    const float* bsrc = db + (size_t)(n0 + srow) * I_ + oct0 * 8;
    short8v* wA0 = (short8v*)&As[(oct0 * BM + srow) * 8];
    short8v* wA1 = (short8v*)&As[((oct0 + 2) * BM + srow) * 8];
    short8v* wB0 = (short8v*)&Bs[(oct0 * BM + srow) * 8];
    short8v* wB1 = (short8v*)&Bs[((oct0 + 2) * BM + srow) * 8];

    const int wid = tid >> 6, lane = tid & 63;
    const int l16 = lane & 15, koct = lane >> 4;
    const int aoff = koct * BM + wid * 32 + l16;
    const int boff = koct * BM + l16;

    f32x4 acc[2][8];
#pragma unroll
    for (int i = 0; i < 2; ++i)
#pragma unroll
        for (int j = 0; j < 8; ++j) acc[i][j] = (f32x4){0.f, 0.f, 0.f, 0.f};

    short8v raa, rab;
    float4 rb0, rb1, rb2, rb3;
#define LOADREGS2(K0) { \
    raa = *(const short8v*)(hsrc + (K0)); rab = *(const short8v*)(hsrc + (K0) + 16); \
    rb0 = *(const float4*)(bsrc + (K0));      rb1 = *(const float4*)(bsrc + (K0) + 4); \
    rb2 = *(const float4*)(bsrc + (K0) + 16); rb3 = *(const float4*)(bsrc + (K0) + 20); }

    LOADREGS2(0);
    for (int k0 = 0; k0 < I_; k0 += BKK) {
        __syncthreads();
        *wA0 = raa;
        *wA1 = rab;
        *wB0 = pack8(rb0, rb1);
        *wB1 = pack8(rb2, rb3);
        __syncthreads();
        if (k0 + BKK < I_) LOADREGS2(k0 + BKK);
        short8v a0 = *(const short8v*)&As[aoff * 8];
        short8v a1 = *(const short8v*)&As[(aoff + 16) * 8];
#pragma unroll
        for (int j = 0; j < 8; ++j) {
            short8v b = *(const short8v*)&Bs[(boff + j * 16) * 8];
            acc[0][j] = __builtin_amdgcn_mfma_f32_16x16x32_bf16(a0, b, acc[0][j], 0, 0, 0);
            acc[1][j] = __builtin_amdgcn_mfma_f32_16x16x32_bf16(a1, b, acc[1][j], 0, 0, 0);
        }
    }

    const int r0 = (lane >> 4) * 4;
#pragma unroll
    for (int mr = 0; mr < 2; ++mr)
#pragma unroll
        for (int j = 0; j < 8; ++j)
#pragma unroll
            for (int r = 0; r < 4; ++r) {
                int m = wid * 32 + mr * 16 + r0 + r;
                if (m < rows)
                    atomicAdd(&out[(size_t)tokS[m] * D_ + n0 + j * 16 + l16],
                              wtS[m] * acc[mr][j][r]);
            }
}

// ------------------------------------------------------------------ launch --

extern "C" void kernel_launch(void* const* d_in, const int* in_sizes, int n_in,
                              void* d_out, int out_size, void* d_ws, size_t ws_size,
                              hipStream_t stream)
{
    const float* hidden = (const float*)d_in[0];
    const int*   idx    = (const int*)  d_in[1];   // int32 or int64 (detected)
    const float* wts    = (const float*)d_in[2];
    const float* gup    = (const float*)d_in[3];
    const float* down   = (const float*)d_in[4];
    float* out = (float*)d_out;
    int*   w   = (int*)d_ws;

    hipMemsetAsync(d_ws, 0, 4096, stream);                              // header
    hipMemsetAsync(d_out, 0, (size_t)T_ * D_ * sizeof(float), stream);  // atomic target

    detect_idx64_kernel<<<1, 64, 0, stream>>>(idx, w);
    hist_kernel<<<NBLK, 256, 0, stream>>>(idx, w);
    scan_kernel<<<1, 64, 0, stream>>>(w);
    scatter_kernel<<<NBLK, 256, 0, stream>>>(idx, wts, w);

    unsigned short* H = (unsigned short*)((char*)d_ws + H_OFF);
    dim3 g1(I_ / 64, MAXT), g2(D_ / 128, MAXT);
    gemm1_mfma<<<g1, 256, 0, stream>>>(hidden, gup, w, H);
    gemm2_mfma<<<g2, 256, 0, stream>>>(H, down, w, out);
}

// Round 14
// 626.273 us; speedup vs baseline: 1.1264x; 1.1264x over previous
//
#include <hip/hip_runtime.h>
#include <hip/hip_bf16.h>

// FujiRoutedExperts: E=32, D=1024, I=512, T=4096, K=8 (all fp32 in/out)
#define E_   32
#define D_   1024
#define I_   512
#define T_   4096
#define KTOP 8
#define TK   (T_*KTOP)          // 32768 gathered (token, slot) rows

// MFMA GEMM tiling: 128-row tiles, BK=32 (one 16x16x32 MFMA K-depth)
#define BM   128
#define BKK  32
#define PAD  36                 // LDS row stride in shorts (72 B). Read: 16-lane
                                // groups hit bases (18r)%32 - 16 distinct evens,
                                // every bank covered exactly 2x = free (m136).
                                // Write: 16 ranges of 16 banks, 8x uniform = min.
#define MAXT (TK/BM + E_)       // 288 worst-case row-tiles
#define TCHUNK (MAXT/8)         // 36 tiles per XCD chunk
#define NBLK 128                // routing blocks (TK / 256)

// Workspace layout:
//  w[0]       idx-is-int64 flag
//  w[96..128] expert segment offsets (off[32]=TK) | w[129] tile count
//  byte 1024   int2 tiles[MAXT]                (2304 B)
//  byte 4096   int  blockHist[NBLK][E_]        (16 KB)
//  byte 20480  int  blockBase[NBLK][E_]        (16 KB)
//  byte 36864  int   tok[TK]                   (128 KB)
//  byte 167936 float wt[TK]                    (128 KB)
//  byte 524288 bf16  H[TK][I_]                 (32 MB)
#define TILES_OFF 1024
#define HIST_OFF  4096
#define BASE_OFF  20480
#define TOK_OFF   36864
#define WT_OFF    167936
#define H_OFF     524288

typedef __attribute__((ext_vector_type(8))) short short8v;   // 8 bf16 = 4 VGPR
typedef __attribute__((ext_vector_type(4))) float f32x4;     // MFMA acc

// fp32 -> bf16; compiler pairs scalar casts into v_cvt_pk_bf16_f32 (m240).
__device__ inline unsigned short f2bf(float x) {
    __hip_bfloat16 h = __float2bfloat16(x);
    union { __hip_bfloat16 h; unsigned short u; } c; c.h = h; return c.u;
}
__device__ inline short8v pack8(float4 a, float4 b) {
    short8v r;
    r[0]=(short)f2bf(a.x); r[1]=(short)f2bf(a.y); r[2]=(short)f2bf(a.z); r[3]=(short)f2bf(a.w);
    r[4]=(short)f2bf(b.x); r[5]=(short)f2bf(b.y); r[6]=(short)f2bf(b.z); r[7]=(short)f2bf(b.w);
    return r;
}

// ---------------------------------------------------------------- routing ---

// int64 indices (values 0..31, little-endian) have all odd int32 words zero.
__global__ void detect_idx64_kernel(const int* __restrict__ idx32, int* w) {
    const int lane = threadIdx.x;      // 64 threads
    int bad = 0;
#pragma unroll
    for (int j = 0; j < 4; ++j) bad |= idx32[2 * (lane + 64 * j) + 1];
    int allz = __all(bad == 0);
    if (lane == 0) w[0] = allz ? 1 : 0;
}

// Per-block 32-bin histogram in LDS; each block owns its global hist row.
__global__ __launch_bounds__(256) void hist_kernel(const int* __restrict__ idx32, int* w) {
    __shared__ int h[E_];
    const int tid = threadIdx.x, b = blockIdx.x;
    if (tid < E_) h[tid] = 0;
    __syncthreads();
    int i = b * 256 + tid;
    int e = w[0] ? idx32[2*i] : idx32[i];
    atomicAdd(&h[e], 1);               // LDS atomic: fast
    __syncthreads();
    if (tid < E_) ((int*)((char*)w + HIST_OFF))[b * E_ + tid] = h[tid];
}

// One wave. Lane e: serial scan over NBLK blocks -> per-block bases + expert
// totals; shfl scan over experts -> segment offsets; then emit tile list.
__global__ void scan_kernel(int* w) {
    const int lane = threadIdx.x;      // 64 threads
    int* hist = (int*)((char*)w + HIST_OFF);
    int* base = (int*)((char*)w + BASE_OFF);
    int cnt = 0;
    if (lane < E_) {
        for (int b = 0; b < NBLK; ++b) { base[b*E_ + lane] = cnt; cnt += hist[b*E_ + lane]; }
    }
    int x = cnt;
#pragma unroll
    for (int d = 1; d < 32; d <<= 1) {
        int v = __shfl_up(x, d, 64);
        if (lane >= d) x += v;
    }
    int excl = x - cnt;                // expert segment start
    if (lane < E_) {
        w[96 + lane] = excl;
        for (int b = 0; b < NBLK; ++b) base[b*E_ + lane] += excl;
    }
    if (lane == E_ - 1) w[96 + E_] = x;

    int nt_e = (lane < E_) ? (cnt + BM - 1) / BM : 0;
    int y = nt_e;
#pragma unroll
    for (int d = 1; d < 32; d <<= 1) {
        int v = __shfl_up(y, d, 64);
        if (lane >= d) y += v;
    }
    int texcl = y - nt_e;
    if (lane == E_ - 1) w[129] = y;
    int2* tiles = (int2*)((char*)w + TILES_OFF);
    for (int i = 0; i < nt_e; ++i)
        tiles[texcl + i] = make_int2(lane, excl + i * BM);
}

// Positions from per-block bases + LDS cursors (no global atomics).
__global__ __launch_bounds__(256) void scatter_kernel(const int* __restrict__ idx32,
                               const float* __restrict__ wts, int* w) {
    __shared__ int cur[E_];
    const int tid = threadIdx.x, b = blockIdx.x;
    if (tid < E_) cur[tid] = ((int*)((char*)w + BASE_OFF))[b * E_ + tid];
    __syncthreads();
    int i = b * 256 + tid;
    int e = w[0] ? idx32[2*i] : idx32[i];
    int pos = atomicAdd(&cur[e], 1);   // LDS atomic
    ((int*)  ((char*)w + TOK_OFF))[pos] = i >> 3;   // i / KTOP
    ((float*)((char*)w + WT_OFF))[pos]  = wts[i];
}

// --------------------------------------------------------------- GEMM1 ------
// H[row, n] = silu(x.Wgate[n]) * (x.Wup[n]); M=TK (gathered), N=I_, K=D_.
// Coalesced staging (R3): 4 lanes per row, 128B contiguous per 4 lanes.
// LDS rows PAD=36 shorts: conflict-free both sides (see PAD comment).
// XCD decode: slot s -> chunk s&7 (XCD round-robin), col-block (s>>3)&7,
// tile-in-chunk s>>6. The 8 col-blocks of one tile are temporally adjacent
// on one XCD -> A-tile + gather list hit its L2 instead of 8x HBM. Perf-only.
__global__ __launch_bounds__(256) void gemm1_mfma(
    const float* __restrict__ hidden, const float* __restrict__ gup,
    const int* __restrict__ w, unsigned short* __restrict__ H)
{
    const int s = blockIdx.y * 8 + blockIdx.x;      // dispatch slot 0..2303
    const int tile = (s & 7) * TCHUNK + (s >> 6);   // 0..287
    const int cb   = (s >> 3) & 7;                  // col-block 0..7
    if (tile >= w[129]) return;
    int2 tl = ((const int2*)((const char*)w + TILES_OFF))[tile];
    const int e = tl.x, rs = tl.y;
    const int rows = min(w[96 + e + 1] - rs, BM);
    const int* tok = (const int*)((const char*)w + TOK_OFF);

    __shared__ short As[BM * PAD];
    __shared__ short Bs[BM * PAD];
    __shared__ int tokS[BM];

    const int tid = threadIdx.x;
    if (tid < BM) tokS[tid] = tok[rs + min(tid, rows - 1)];
    __syncthreads();

    const int n0 = cb * 64;                         // SwiGLU col block (<512)
    const float* gb = gup + (size_t)e * (2 * I_) * D_;

    // staging: thread -> (row = tid>>2, 8-float group = tid&3); 2 rows each
    const int crow = tid >> 2, ckg = tid & 3;
    const float* aptr0 = hidden + (size_t)tokS[crow]      * D_ + ckg * 8;
    const float* aptr1 = hidden + (size_t)tokS[crow + 64] * D_ + ckg * 8;
    const float* bptr0 = gb + (size_t)(n0 + crow)      * D_ + ckg * 8;  // gate
    const float* bptr1 = gb + (size_t)(I_ + n0 + crow) * D_ + ckg * 8;  // up
    short8v* wA0 = (short8v*)&As[crow * PAD + ckg * 8];
    short8v* wA1 = (short8v*)&As[(crow + 64) * PAD + ckg * 8];
    short8v* wB0 = (short8v*)&Bs[crow * PAD + ckg * 8];
    short8v* wB1 = (short8v*)&Bs[(crow + 64) * PAD + ckg * 8];

    const int wid = tid >> 6, lane = tid & 63;
    const int l16 = lane & 15, lk = (lane >> 4) * 8;
    const int aoff = (wid * 32 + l16) * PAD + lk;   // A frag, row-block 0
    const int boff = l16 * PAD + lk;                // B^T frag, col-block 0

    f32x4 acc[2][8];
#pragma unroll
    for (int i = 0; i < 2; ++i)
#pragma unroll
        for (int j = 0; j < 8; ++j) acc[i][j] = (f32x4){0.f, 0.f, 0.f, 0.f};

    float4 ra0a, ra0b, ra1a, ra1b, rb0a, rb0b, rb1a, rb1b;
#define LOADREGS1(K0) { \
    ra0a = *(const float4*)(aptr0 + (K0)); ra0b = *(const float4*)(aptr0 + (K0) + 4); \
    ra1a = *(const float4*)(aptr1 + (K0)); ra1b = *(const float4*)(aptr1 + (K0) + 4); \
    rb0a = *(const float4*)(bptr0 + (K0)); rb0b = *(const float4*)(bptr0 + (K0) + 4); \
    rb1a = *(const float4*)(bptr1 + (K0)); rb1b = *(const float4*)(bptr1 + (K0) + 4); }

    LOADREGS1(0);
    for (int k0 = 0; k0 < D_; k0 += BKK) {
        __syncthreads();
        *wA0 = pack8(ra0a, ra0b);
        *wA1 = pack8(ra1a, ra1b);
        *wB0 = pack8(rb0a, rb0b);
        *wB1 = pack8(rb1a, rb1b);
        __syncthreads();
        if (k0 + BKK < D_) LOADREGS1(k0 + BKK);
        short8v a0 = *(const short8v*)&As[aoff];
        short8v a1 = *(const short8v*)&As[aoff + 16 * PAD];
#pragma unroll
        for (int j = 0; j < 8; ++j) {
            short8v b = *(const short8v*)&Bs[boff + j * 16 * PAD];
            acc[0][j] = __builtin_amdgcn_mfma_f32_16x16x32_bf16(a0, b, acc[0][j], 0, 0, 0);
            acc[1][j] = __builtin_amdgcn_mfma_f32_16x16x32_bf16(a1, b, acc[1][j], 0, 0, 0);
        }
    }

    // SwiGLU epilogue: frag j is gate cols, j+4 is up (same lanes/rows).
    const int r0 = (lane >> 4) * 4;
#pragma unroll
    for (int mr = 0; mr < 2; ++mr)
#pragma unroll
        for (int j = 0; j < 4; ++j)
#pragma unroll
            for (int r = 0; r < 4; ++r) {
                int m = wid * 32 + mr * 16 + r0 + r;
                if (m < rows) {
                    float g = acc[mr][j][r], u = acc[mr][j + 4][r];
                    float sgl = g / (1.f + __expf(-g));
                    H[(size_t)(rs + m) * I_ + n0 + j * 16 + l16] = f2bf(sgl * u);
                }
            }
}

// --------------------------------------------------------------- GEMM2 ------
// out[tok,n] += wt * (H[row].Wd[n]); M=TK, N=D_, K=I_. Same structure;
// 8 col-blocks of 128 (D_/128 = 8 -- NOT 16; the 16-block decode was the
// R10 crash: cb up to 15 read down/out rows up to 2047 >= D_=1024, OOB).
// Same bijective decode as gemm1: 2304 slots = 288 tiles x 8 col-blocks.
__global__ __launch_bounds__(256) void gemm2_mfma(
    const unsigned short* __restrict__ H, const float* __restrict__ down,
    const int* __restrict__ w, float* __restrict__ out)
{
    const int s = blockIdx.y * 8 + blockIdx.x;      // dispatch slot 0..2303
    const int tile = (s & 7) * TCHUNK + (s >> 6);   // 0..287
    const int cb   = (s >> 3) & 7;                  // col-block 0..7
    if (tile >= w[129]) return;
    int2 tl = ((const int2*)((const char*)w + TILES_OFF))[tile];
    const int e = tl.x, rs = tl.y;
    const int rows = min(w[96 + e + 1] - rs, BM);
    const int*   tok = (const int*)  ((const char*)w + TOK_OFF);
    const float* wts = (const float*)((const char*)w + WT_OFF);

    __shared__ short As[BM * PAD];
    __shared__ short Bs[BM * PAD];
    __shared__ int   tokS[BM];
    __shared__ float wtS[BM];

    const int tid = threadIdx.x;
    if (tid < BM) {
        tokS[tid] = tok[rs + min(tid, rows - 1)];
        wtS[tid]  = (tid < rows) ? wts[rs + tid] : 0.f;
    }
    __syncthreads();

    const int n0 = cb * 128;                        // out col block (<1024)
    const float* db = down + (size_t)e * D_ * I_;

    const int crow = tid >> 2, ckg = tid & 3;
    // A = H (already bf16): straight 16B copies; clamp final-tile overrun.
    const short* ha0 = (const short*)H + (size_t)min(rs + crow,      TK - 1) * I_ + ckg * 8;
    const short* ha1 = (const short*)H + (size_t)min(rs + crow + 64, TK - 1) * I_ + ckg * 8;
    const float* bptr0 = db + (size_t)(n0 + crow)      * I_ + ckg * 8;
    const float* bptr1 = db + (size_t)(n0 + crow + 64) * I_ + ckg * 8;
    short8v* wA0 = (short8v*)&As[crow * PAD + ckg * 8];
    short8v* wA1 = (short8v*)&As[(crow + 64) * PAD + ckg * 8];
    short8v* wB0 = (short8v*)&Bs[crow * PAD + ckg * 8];
    short8v* wB1 = (short8v*)&Bs[(crow + 64) * PAD + ckg * 8];

    const int wid = tid >> 6, lane = tid & 63;
    const int l16 = lane & 15, lk = (lane >> 4) * 8;
    const int aoff = (wid * 32 + l16) * PAD + lk;
    const int boff = l16 * PAD + lk;

    f32x4 acc[2][8];
#pragma unroll
    for (int i = 0; i < 2; ++i)
#pragma unroll
        for (int j = 0; j < 8; ++j) acc[i][j] = (f32x4){0.f, 0.f, 0.f, 0.f};

    short8v raa, rab;
    float4 rb0a, rb0b, rb1a, rb1b;
#define LOADREGS2(K0) { \
    raa = *(const short8v*)(ha0 + (K0)); rab = *(const short8v*)(ha1 + (K0)); \
    rb0a = *(const float4*)(bptr0 + (K0)); rb0b = *(const float4*)(bptr0 + (K0) + 4); \
    rb1a = *(const float4*)(bptr1 + (K0)); rb1b = *(const float4*)(bptr1 + (K0) + 4); }

    LOADREGS2(0);
    for (int k0 = 0; k0 < I_; k0 += BKK) {
        __syncthreads();
        *wA0 = raa;
        *wA1 = rab;
        *wB0 = pack8(rb0a, rb0b);
        *wB1 = pack8(rb1a, rb1b);
        __syncthreads();
        if (k0 + BKK < I_) LOADREGS2(k0 + BKK);
        short8v a0 = *(const short8v*)&As[aoff];
        short8v a1 = *(const short8v*)&As[aoff + 16 * PAD];
#pragma unroll
        for (int j = 0; j < 8; ++j) {
            short8v b = *(const short8v*)&Bs[boff + j * 16 * PAD];
            acc[0][j] = __builtin_amdgcn_mfma_f32_16x16x32_bf16(a0, b, acc[0][j], 0, 0, 0);
            acc[1][j] = __builtin_amdgcn_mfma_f32_16x16x32_bf16(a1, b, acc[1][j], 0, 0, 0);
        }
    }

    const int r0 = (lane >> 4) * 4;
#pragma unroll
    for (int mr = 0; mr < 2; ++mr)
#pragma unroll
        for (int j = 0; j < 8; ++j)
#pragma unroll
            for (int r = 0; r < 4; ++r) {
                int m = wid * 32 + mr * 16 + r0 + r;
                if (m < rows)
                    atomicAdd(&out[(size_t)tokS[m] * D_ + n0 + j * 16 + l16],
                              wtS[m] * acc[mr][j][r]);
            }
}

// ------------------------------------------------------------------ launch --

extern "C" void kernel_launch(void* const* d_in, const int* in_sizes, int n_in,
                              void* d_out, int out_size, void* d_ws, size_t ws_size,
                              hipStream_t stream)
{
    const float* hidden = (const float*)d_in[0];
    const int*   idx    = (const int*)  d_in[1];   // int32 or int64 (detected)
    const float* wts    = (const float*)d_in[2];
    const float* gup    = (const float*)d_in[3];
    const float* down   = (const float*)d_in[4];
    float* out = (float*)d_out;
    int*   w   = (int*)d_ws;

    hipMemsetAsync(d_ws, 0, 4096, stream);                              // header
    hipMemsetAsync(d_out, 0, (size_t)T_ * D_ * sizeof(float), stream);  // atomic target

    detect_idx64_kernel<<<1, 64, 0, stream>>>(idx, w);
    hist_kernel<<<NBLK, 256, 0, stream>>>(idx, w);
    scan_kernel<<<1, 64, 0, stream>>>(w);
    scatter_kernel<<<NBLK, 256, 0, stream>>>(idx, wts, w);

    unsigned short* H = (unsigned short*)((char*)d_ws + H_OFF);
    dim3 g1(8, MAXT), g2(8, MAXT);
    gemm1_mfma<<<g1, 256, 0, stream>>>(hidden, gup, w, H);
    gemm2_mfma<<<g2, 256, 0, stream>>>(H, down, w, out);
}